// Round 5
// baseline (824.706 us; speedup 1.0000x reference)
//
#include <hip/hip_runtime.h>
#include <hip/hip_bf16.h>

#define NN 384
#define DP 128
#define NHEAD 4
#define CH 32
#define HCC 128

typedef __hip_bfloat16 bf16;
typedef __bf16 bf16x8 __attribute__((ext_vector_type(8)));
typedef __bf16 bf16x4 __attribute__((ext_vector_type(4)));
typedef float floatx4 __attribute__((ext_vector_type(4)));

#define WSTRIDE 136   // out_kernel weight LDS stride
#define PSTR 392      // attn P-strip stride in bf16 elems (rows 16B-aligned, 2-way banks)

__device__ __forceinline__ float b2f(bf16 x){ return __bfloat162float(x); }
__device__ __forceinline__ bf16 f2b(float x){ return __float2bfloat16(x); }

// Prep: Wt[col][d] = bf16(Wqkv[d][col]) with q-scale folded into cols 0..127
__global__ __launch_bounds__(256) void wt_kernel(
    const float* __restrict__ Wqkv, __bf16* __restrict__ Wt)
{
  const float qscale = 0.17677669529663687f; // 1/sqrt(32)
  int idx = blockIdx.x * 256 + threadIdx.x;   // 49152 total
  int d = idx / NN, col = idx - d * NN;
  float v = Wqkv[idx];
  if (col < HCC) v *= qscale;
  Wt[col * DP + d] = (__bf16)v;
}

// Prep: WgT[h][d] = Wg[d][h]; WoT[d][e] = Wo[e][d]  (both 128x128)
__global__ __launch_bounds__(256) void wgo_kernel(
    const float* __restrict__ Wg, const float* __restrict__ Wo,
    __bf16* __restrict__ WgT, __bf16* __restrict__ WoT)
{
  int idx = blockIdx.x * 256 + threadIdx.x;   // 16384 total
  int r = idx >> 7, c = idx & 127;
  WgT[idx] = (__bf16)Wg[c * 128 + r];
  WoT[idx] = (__bf16)Wo[c * 128 + r];
}

// Kernel A: LayerNorm + triangle bias. 32-lane group per position, float4 lanes.
__global__ __launch_bounds__(256) void ln_bias_kernel(
    const float* __restrict__ Zr, const float* __restrict__ lnw,
    const float* __restrict__ lnb, const float* __restrict__ Wb,
    bf16* __restrict__ Zn, float* __restrict__ bias)
{
  int t = threadIdx.x;
  int grp = t >> 5, lane32 = t & 31;
  int pos = blockIdx.x * 8 + grp;
  size_t base = (size_t)pos * DP;
  const float4 x = *(const float4*)(Zr + base + lane32 * 4);
  float s  = x.x + x.y + x.z + x.w;
  float s2 = x.x*x.x + x.y*x.y + x.z*x.z + x.w*x.w;
  #pragma unroll
  for (int m = 1; m < 32; m <<= 1){ s += __shfl_xor(s, m); s2 += __shfl_xor(s2, m); }
  float mean = s * (1.0f / DP);
  float var  = s2 * (1.0f / DP) - mean * mean;
  float rstd = rsqrtf(var + 1e-5f);
  const float4 w4 = *(const float4*)(lnw + lane32 * 4);
  const float4 b4 = *(const float4*)(lnb + lane32 * 4);
  float z0 = (x.x - mean) * rstd * w4.x + b4.x;
  float z1 = (x.y - mean) * rstd * w4.y + b4.y;
  float z2 = (x.z - mean) * rstd * w4.z + b4.z;
  float z3 = (x.w - mean) * rstd * w4.w + b4.w;
  bf16x4 zb = { (__bf16)z0, (__bf16)z1, (__bf16)z2, (__bf16)z3 };
  *(bf16x4*)((__bf16*)Zn + base + lane32 * 4) = zb;
  const float4 wb0 = *(const float4*)(Wb + (lane32 * 4 + 0) * NHEAD);
  const float4 wb1 = *(const float4*)(Wb + (lane32 * 4 + 1) * NHEAD);
  const float4 wb2 = *(const float4*)(Wb + (lane32 * 4 + 2) * NHEAD);
  const float4 wb3 = *(const float4*)(Wb + (lane32 * 4 + 3) * NHEAD);
  float p0 = z0*wb0.x + z1*wb1.x + z2*wb2.x + z3*wb3.x;
  float p1 = z0*wb0.y + z1*wb1.y + z2*wb2.y + z3*wb3.y;
  float p2 = z0*wb0.z + z1*wb1.z + z2*wb2.z + z3*wb3.z;
  float p3 = z0*wb0.w + z1*wb1.w + z2*wb2.w + z3*wb3.w;
  #pragma unroll
  for (int m = 1; m < 32; m <<= 1){
    p0 += __shfl_xor(p0, m); p1 += __shfl_xor(p1, m);
    p2 += __shfl_xor(p2, m); p3 += __shfl_xor(p3, m);
  }
  if (lane32 == 0){
    bias[0 * NN * NN + pos] = p0;
    bias[1 * NN * NN + pos] = p1;
    bias[2 * NN * NN + pos] = p2;
    bias[3 * NN * NN + pos] = p3;
  }
}

// Kernel B1: qkv = Zn @ Wqkv as one big GEMM, no LDS, packed stores.
// q_g/k_g: [i*384+n][128] bf16 (q pre-scaled). v_g: [i][c(128)][n(384)] bf16.
__global__ __launch_bounds__(256) void qkv_gemm(
    const __bf16* __restrict__ Zn, const __bf16* __restrict__ Wt,
    __bf16* __restrict__ q_g, __bf16* __restrict__ k_g, __bf16* __restrict__ v_g)
{
  int i = blockIdx.x >> 1;
  int half = blockIdx.x & 1;
  int t = threadIdx.x;
  int wv = t >> 6, lane = t & 63;
  int m16 = lane & 15, quad = lane >> 4;

  int mrow0 = half * 192 + wv * 48;   // this wave: 3 mtiles = rows mrow0..mrow0+47 (within i)

  // preload Zn frags for 3 mtiles (dual-use as A- or B-operand)
  bf16x8 zf[3][4];
  #pragma unroll
  for (int mt = 0; mt < 3; mt++){
    const __bf16* zrow = Zn + (size_t)(i * NN + mrow0 + mt * 16 + m16) * DP + quad * 8;
    #pragma unroll
    for (int kc = 0; kc < 4; kc++) zf[mt][kc] = *(const bf16x8*)(zrow + kc * 32);
  }

  for (int nt = 0; nt < 24; nt++){
    bf16x8 wf[4];
    const __bf16* wrow = Wt + (size_t)(nt * 16 + m16) * DP + quad * 8;
    #pragma unroll
    for (int kc = 0; kc < 4; kc++) wf[kc] = *(const bf16x8*)(wrow + kc * 32);
    #pragma unroll
    for (int mt = 0; mt < 3; mt++){
      floatx4 acc = {0.f, 0.f, 0.f, 0.f};
      if (nt < 16){
        // q/k: D[m=w_col][n=zn_row] -> lane: fixed zn_row(m16), 4 consecutive w_cols
        #pragma unroll
        for (int kc = 0; kc < 4; kc++)
          acc = __builtin_amdgcn_mfma_f32_16x16x32_bf16(wf[kc], zf[mt][kc], acc, 0, 0, 0);
        bf16x4 pk = { (__bf16)acc[0], (__bf16)acc[1], (__bf16)acc[2], (__bf16)acc[3] };
        int row = i * NN + mrow0 + mt * 16 + m16;
        if (nt < 8)
          *(bf16x4*)(q_g + (size_t)row * HCC + nt * 16 + quad * 4) = pk;
        else
          *(bf16x4*)(k_g + (size_t)row * HCC + (nt - 8) * 16 + quad * 4) = pk;
      } else {
        // v: D[m=zn_row][n=w_col] -> lane: fixed w_col(m16), 4 consecutive zn_rows
        #pragma unroll
        for (int kc = 0; kc < 4; kc++)
          acc = __builtin_amdgcn_mfma_f32_16x16x32_bf16(zf[mt][kc], wf[kc], acc, 0, 0, 0);
        bf16x4 pk = { (__bf16)acc[0], (__bf16)acc[1], (__bf16)acc[2], (__bf16)acc[3] };
        int c = (nt - 16) * 16 + m16;
        *(bf16x4*)(v_g + ((size_t)i * HCC + c) * NN + mrow0 + mt * 16 + quad * 4) = pk;
      }
    }
  }
}

// Kernel B2: attention per (i,h). S^T = K@Q^T (bias as C-operand), packed softmax,
// P via wave-private LDS strip, O^T = V^T@P^T for packed stores. No barriers in loop.
__global__ __launch_bounds__(256, 2) void attn_kernel(
    const __bf16* __restrict__ q_g, const __bf16* __restrict__ k_g,
    const __bf16* __restrict__ v_g, const float* __restrict__ Zm,
    const float* __restrict__ bias, __bf16* __restrict__ wa)
{
  __shared__ __align__(16) __bf16 ps[4 * 16 * PSTR];   // per-wave P strip [16 q][384 k]
  __shared__ __align__(16) float maskb[NN];

  int i = blockIdx.x >> 2;
  int h = blockIdx.x & 3;
  int t = threadIdx.x;
  int wv = t >> 6, lane = t & 63;
  int m16 = lane & 15, quad = lane >> 4;

  for (int k = t; k < NN; k += 256)
    maskb[k] = (Zm[(size_t)i * NN + k] - 1.0f) * 1e9f;
  __syncthreads();

  __bf16* pw = ps + wv * 16 * PSTR;
  const float* bh = bias + (size_t)h * NN * NN;

  for (int s = 0; s < 6; s++){
    int strip = wv * 6 + s;
    int qrow = strip * 16 + m16;             // this lane's q row (within i)
    // Q as B-operand
    bf16x8 qf = *(const bf16x8*)(q_g + (size_t)(i * NN + qrow) * HCC + h * CH + quad * 8);
    // S^T tiles: rows k (quad*4+reg), cols q (m16); C-init = bias + mask
    floatx4 sacc[24];
    #pragma unroll
    for (int kt = 0; kt < 24; kt++){
      int k0 = kt * 16 + quad * 4;
      floatx4 cin = *(const floatx4*)(bh + (size_t)qrow * NN + k0);
      floatx4 mk  = *(const floatx4*)(maskb + k0);
      cin += mk;
      bf16x8 kf = *(const bf16x8*)(k_g + (size_t)(i * NN + kt * 16 + m16) * HCC + h * CH + quad * 8);
      sacc[kt] = __builtin_amdgcn_mfma_f32_16x16x32_bf16(kf, qf, cin, 0, 0, 0);
    }
    // row max (per lane: all 96 values belong to q = m16)
    float mx = -1e30f;
    #pragma unroll
    for (int kt = 0; kt < 24; kt++){
      mx = fmaxf(mx, fmaxf(fmaxf(sacc[kt][0], sacc[kt][1]),
                           fmaxf(sacc[kt][2], sacc[kt][3])));
    }
    mx = fmaxf(mx, __shfl_xor(mx, 16));
    mx = fmaxf(mx, __shfl_xor(mx, 32));
    // exp, sum, packed P writes (wave-private -> no barrier)
    float sm = 0.f;
    #pragma unroll
    for (int kt = 0; kt < 24; kt++){
      float p0 = __expf(sacc[kt][0] - mx);
      float p1 = __expf(sacc[kt][1] - mx);
      float p2 = __expf(sacc[kt][2] - mx);
      float p3 = __expf(sacc[kt][3] - mx);
      sm += (p0 + p1) + (p2 + p3);
      bf16x4 pk = { (__bf16)p0, (__bf16)p1, (__bf16)p2, (__bf16)p3 };
      *(bf16x4*)(pw + m16 * PSTR + kt * 16 + quad * 4) = pk;
    }
    sm += __shfl_xor(sm, 16);
    sm += __shfl_xor(sm, 32);
    float inv = 1.0f / sm;
    // O^T = V^T @ P^T: rows c (quad*4+reg), cols q (m16)
    floatx4 oacc[2] = {{0.f,0.f,0.f,0.f},{0.f,0.f,0.f,0.f}};
    #pragma unroll
    for (int kc = 0; kc < 12; kc++){
      bf16x8 pa = *(const bf16x8*)(pw + m16 * PSTR + kc * 32 + quad * 8);
      #pragma unroll
      for (int ct = 0; ct < 2; ct++){
        bf16x8 vb = *(const bf16x8*)(v_g + ((size_t)i * HCC + h * CH + ct * 16 + m16) * NN
                                          + kc * 32 + quad * 8);
        oacc[ct] = __builtin_amdgcn_mfma_f32_16x16x32_bf16(vb, pa, oacc[ct], 0, 0, 0);
      }
    }
    #pragma unroll
    for (int ct = 0; ct < 2; ct++){
      bf16x4 pk = { (__bf16)(oacc[ct][0] * inv), (__bf16)(oacc[ct][1] * inv),
                    (__bf16)(oacc[ct][2] * inv), (__bf16)(oacc[ct][3] * inv) };
      *(bf16x4*)(wa + (size_t)(i * NN + qrow) * HCC + h * CH + ct * 16 + quad * 4) = pk;
    }
  }
}

// Kernel C (MFMA): gate = sigmoid(Zn@Wg + gb); out = (gate*wa)@Wo + Zr + ob
__global__ __launch_bounds__(256, 1) void out_kernel(
    const float* __restrict__ Zr, const __bf16* __restrict__ Zn,
    const __bf16* __restrict__ wa, const __bf16* __restrict__ WgT,
    const float* __restrict__ gb, const __bf16* __restrict__ WoT,
    const float* __restrict__ ob, float* __restrict__ out)
{
  __shared__ __align__(16) __bf16 wgs[128 * WSTRIDE];
  __shared__ __align__(16) __bf16 wos[128 * WSTRIDE];
  __shared__ __align__(16) __bf16 gsh[4][16 * WSTRIDE];
  __shared__ float gbs[HCC], obs[DP];

  int t = threadIdx.x;
  int wv = t >> 6, lane = t & 63;
  int m16 = lane & 15, quad = lane >> 4;

  for (int idx = t * 8; idx < 128 * 128; idx += 256 * 8){
    int r = idx >> 7, c = idx & 127;
    *(bf16x8*)(wgs + r * WSTRIDE + c) = *(const bf16x8*)(WgT + idx);
    *(bf16x8*)(wos + r * WSTRIDE + c) = *(const bf16x8*)(WoT + idx);
  }
  if (t < 128){ gbs[t] = gb[t]; obs[t] = ob[t]; }
  __syncthreads();

  int mbase = blockIdx.x * 128;
  __bf16* gstrip = gsh[wv];

  for (int sp = 0; sp < 2; sp++){
    int row0 = mbase + (sp * 4 + wv) * 16;
    bf16x8 afr[4];
    const __bf16* arow = Zn + (size_t)(row0 + m16) * DP + quad * 8;
    #pragma unroll
    for (int kc = 0; kc < 4; kc++) afr[kc] = *(const bf16x8*)(arow + kc * 32);
    #pragma unroll
    for (int nt = 0; nt < 8; nt++){
      floatx4 acc = {0.f, 0.f, 0.f, 0.f};
      #pragma unroll
      for (int kc = 0; kc < 4; kc++){
        bf16x8 bfr = *(const bf16x8*)(wgs + (nt * 16 + m16) * WSTRIDE + kc * 32 + quad * 8);
        acc = __builtin_amdgcn_mfma_f32_16x16x32_bf16(afr[kc], bfr, acc, 0, 0, 0);
      }
      int col = nt * 16 + m16;
      #pragma unroll
      for (int reg = 0; reg < 4; reg++){
        int row = row0 + quad * 4 + reg;
        float g = 1.0f / (1.0f + __expf(-(acc[reg] + gbs[col])));
        float w = __bfloat162float(wa[(size_t)row * HCC + col]);
        gstrip[(quad * 4 + reg) * WSTRIDE + col] = (__bf16)(g * w);
      }
    }
    bf16x8 gfr[4];
    #pragma unroll
    for (int kc = 0; kc < 4; kc++)
      gfr[kc] = *(const bf16x8*)(gstrip + m16 * WSTRIDE + kc * 32 + quad * 8);
    #pragma unroll
    for (int nt = 0; nt < 8; nt++){
      floatx4 acc = {0.f, 0.f, 0.f, 0.f};
      #pragma unroll
      for (int kc = 0; kc < 4; kc++){
        bf16x8 bfr = *(const bf16x8*)(wos + (nt * 16 + m16) * WSTRIDE + kc * 32 + quad * 8);
        acc = __builtin_amdgcn_mfma_f32_16x16x32_bf16(gfr[kc], bfr, acc, 0, 0, 0);
      }
      int col = nt * 16 + m16;
      #pragma unroll
      for (int reg = 0; reg < 4; reg++){
        int row = row0 + quad * 4 + reg;
        size_t off = (size_t)row * DP + col;
        out[off] = Zr[off] + acc[reg] + obs[col];
      }
    }
  }
}

extern "C" void kernel_launch(void* const* d_in, const int* in_sizes, int n_in,
                              void* d_out, int out_size, void* d_ws, size_t ws_size,
                              hipStream_t stream)
{
  const float* Zr   = (const float*)d_in[0];
  const float* Zm   = (const float*)d_in[1];
  const float* lnw  = (const float*)d_in[2];
  const float* lnb  = (const float*)d_in[3];
  const float* Wb   = (const float*)d_in[4];
  const float* Wqkv = (const float*)d_in[5];
  const float* Wg   = (const float*)d_in[6];
  const float* gb   = (const float*)d_in[7];
  const float* Wo   = (const float*)d_in[8];
  const float* ob   = (const float*)d_in[9];
  float* out = (float*)d_out;

  char* ws = (char*)d_ws;
  size_t off = 0;
  bf16*   Zn   = (bf16*)(ws + off);    off += (size_t)NN * NN * DP * 2;     // 37.75 MB
  float*  bias = (float*)(ws + off);   off += (size_t)NHEAD * NN * NN * 4;  //  2.36 MB
  bf16*   wa   = (bf16*)(ws + off);    off += (size_t)NN * NN * HCC * 2;    // 37.75 MB
  __bf16* Wt   = (__bf16*)(ws + off);  off += (size_t)3 * HCC * DP * 2;
  __bf16* WgT  = (__bf16*)(ws + off);  off += (size_t)DP * HCC * 2;
  __bf16* WoT  = (__bf16*)(ws + off);  off += (size_t)HCC * DP * 2;
  __bf16* q_g  = (__bf16*)(ws + off);  off += (size_t)NN * NN * HCC * 2;    // 37.75 MB
  __bf16* k_g  = (__bf16*)(ws + off);  off += (size_t)NN * NN * HCC * 2;    // 37.75 MB
  __bf16* v_g  = (__bf16*)(ws + off);  off += (size_t)NN * HCC * NN * 2;    // 37.75 MB

  wt_kernel<<<(3 * HCC * DP) / 256, 256, 0, stream>>>(Wqkv, Wt);
  wgo_kernel<<<(DP * HCC) / 256, 256, 0, stream>>>(Wg, Wo, WgT, WoT);
  ln_bias_kernel<<<NN * NN / 8, 256, 0, stream>>>(Zr, lnw, lnb, Wb, Zn, bias);
  qkv_gemm<<<NN * 2, 256, 0, stream>>>((const __bf16*)Zn, Wt, q_g, k_g, v_g);
  attn_kernel<<<NN * NHEAD, 256, 0, stream>>>(q_g, k_g, v_g, Zm, bias, (__bf16*)wa);
  out_kernel<<<NN * NN / 128, 256, 0, stream>>>(Zr, (const __bf16*)Zn, (const __bf16*)wa,
                                                WgT, gb, WoT, ob, out);
}

// Round 6
// 797.796 us; speedup vs baseline: 1.0337x; 1.0337x over previous
//
#include <hip/hip_runtime.h>
#include <hip/hip_bf16.h>

#define NN 384
#define DP 128
#define NHEAD 4
#define CH 32
#define HCC 128

typedef __hip_bfloat16 bf16;
typedef __bf16 bf16x8 __attribute__((ext_vector_type(8)));
typedef __bf16 bf16x4 __attribute__((ext_vector_type(4)));
typedef float floatx4 __attribute__((ext_vector_type(4)));

#define WSTRIDE 136   // out_kernel weight LDS stride
#define KSTR 40       // attn K-stage row stride (bf16 elems)
#define PSTR 392      // attn P/V row stride (bf16 elems)

__device__ __forceinline__ float b2f(bf16 x){ return __bfloat162float(x); }

// Prep (fused): Wt[col][d] = bf16(Wqkv[d][col]) (q-scaled); WgT/WoT transposes.
__global__ __launch_bounds__(256) void prep_kernel(
    const float* __restrict__ Wqkv, const float* __restrict__ Wg,
    const float* __restrict__ Wo, __bf16* __restrict__ Wt,
    __bf16* __restrict__ WgT, __bf16* __restrict__ WoT)
{
  const float qscale = 0.17677669529663687f; // 1/sqrt(32)
  int idx = blockIdx.x * 256 + threadIdx.x;   // 49152 total
  int d = idx / NN, col = idx - d * NN;
  float v = Wqkv[idx];
  if (col < HCC) v *= qscale;
  Wt[col * DP + d] = (__bf16)v;
  if (idx < DP * HCC){
    int r = idx >> 7, c = idx & 127;
    WgT[idx] = (__bf16)Wg[c * 128 + r];
    WoT[idx] = (__bf16)Wo[c * 128 + r];
  }
}

// Kernel A: LayerNorm + triangle bias. 32-lane group per position, float4 lanes.
__global__ __launch_bounds__(256) void ln_bias_kernel(
    const float* __restrict__ Zr, const float* __restrict__ lnw,
    const float* __restrict__ lnb, const float* __restrict__ Wb,
    bf16* __restrict__ Zn, float* __restrict__ bias)
{
  int t = threadIdx.x;
  int grp = t >> 5, lane32 = t & 31;
  int pos = blockIdx.x * 8 + grp;
  size_t base = (size_t)pos * DP;
  const float4 x = *(const float4*)(Zr + base + lane32 * 4);
  float s  = x.x + x.y + x.z + x.w;
  float s2 = x.x*x.x + x.y*x.y + x.z*x.z + x.w*x.w;
  #pragma unroll
  for (int m = 1; m < 32; m <<= 1){ s += __shfl_xor(s, m); s2 += __shfl_xor(s2, m); }
  float mean = s * (1.0f / DP);
  float var  = s2 * (1.0f / DP) - mean * mean;
  float rstd = rsqrtf(var + 1e-5f);
  const float4 w4 = *(const float4*)(lnw + lane32 * 4);
  const float4 b4 = *(const float4*)(lnb + lane32 * 4);
  float z0 = (x.x - mean) * rstd * w4.x + b4.x;
  float z1 = (x.y - mean) * rstd * w4.y + b4.y;
  float z2 = (x.z - mean) * rstd * w4.z + b4.z;
  float z3 = (x.w - mean) * rstd * w4.w + b4.w;
  bf16x4 zb = { (__bf16)z0, (__bf16)z1, (__bf16)z2, (__bf16)z3 };
  *(bf16x4*)((__bf16*)Zn + base + lane32 * 4) = zb;
  const float4 wb0 = *(const float4*)(Wb + (lane32 * 4 + 0) * NHEAD);
  const float4 wb1 = *(const float4*)(Wb + (lane32 * 4 + 1) * NHEAD);
  const float4 wb2 = *(const float4*)(Wb + (lane32 * 4 + 2) * NHEAD);
  const float4 wb3 = *(const float4*)(Wb + (lane32 * 4 + 3) * NHEAD);
  float p0 = z0*wb0.x + z1*wb1.x + z2*wb2.x + z3*wb3.x;
  float p1 = z0*wb0.y + z1*wb1.y + z2*wb2.y + z3*wb3.y;
  float p2 = z0*wb0.z + z1*wb1.z + z2*wb2.z + z3*wb3.z;
  float p3 = z0*wb0.w + z1*wb1.w + z2*wb2.w + z3*wb3.w;
  #pragma unroll
  for (int m = 1; m < 32; m <<= 1){
    p0 += __shfl_xor(p0, m); p1 += __shfl_xor(p1, m);
    p2 += __shfl_xor(p2, m); p3 += __shfl_xor(p3, m);
  }
  if (lane32 == 0){
    bias[0 * NN * NN + pos] = p0;
    bias[1 * NN * NN + pos] = p1;
    bias[2 * NN * NN + pos] = p2;
    bias[3 * NN * NN + pos] = p3;
  }
}

// Kernel B1: qkv = Zn @ Wqkv as one big GEMM, no LDS, packed stores.
// q_g/k_g: [i*384+n][128] bf16 (q pre-scaled). v_g: [i][c(128)][n(384)] bf16.
__global__ __launch_bounds__(256) void qkv_gemm(
    const __bf16* __restrict__ Zn, const __bf16* __restrict__ Wt,
    __bf16* __restrict__ q_g, __bf16* __restrict__ k_g, __bf16* __restrict__ v_g)
{
  int i = blockIdx.x >> 1;
  int half = blockIdx.x & 1;
  int t = threadIdx.x;
  int wv = t >> 6, lane = t & 63;
  int m16 = lane & 15, quad = lane >> 4;

  int mrow0 = half * 192 + wv * 48;

  bf16x8 zf[3][4];
  #pragma unroll
  for (int mt = 0; mt < 3; mt++){
    const __bf16* zrow = Zn + (size_t)(i * NN + mrow0 + mt * 16 + m16) * DP + quad * 8;
    #pragma unroll
    for (int kc = 0; kc < 4; kc++) zf[mt][kc] = *(const bf16x8*)(zrow + kc * 32);
  }

  for (int nt = 0; nt < 24; nt++){
    bf16x8 wf[4];
    const __bf16* wrow = Wt + (size_t)(nt * 16 + m16) * DP + quad * 8;
    #pragma unroll
    for (int kc = 0; kc < 4; kc++) wf[kc] = *(const bf16x8*)(wrow + kc * 32);
    #pragma unroll
    for (int mt = 0; mt < 3; mt++){
      floatx4 acc = {0.f, 0.f, 0.f, 0.f};
      if (nt < 16){
        #pragma unroll
        for (int kc = 0; kc < 4; kc++)
          acc = __builtin_amdgcn_mfma_f32_16x16x32_bf16(wf[kc], zf[mt][kc], acc, 0, 0, 0);
        bf16x4 pk = { (__bf16)acc[0], (__bf16)acc[1], (__bf16)acc[2], (__bf16)acc[3] };
        int row = i * NN + mrow0 + mt * 16 + m16;
        if (nt < 8)
          *(bf16x4*)(q_g + (size_t)row * HCC + nt * 16 + quad * 4) = pk;
        else
          *(bf16x4*)(k_g + (size_t)row * HCC + (nt - 8) * 16 + quad * 4) = pk;
      } else {
        #pragma unroll
        for (int kc = 0; kc < 4; kc++)
          acc = __builtin_amdgcn_mfma_f32_16x16x32_bf16(zf[mt][kc], wf[kc], acc, 0, 0, 0);
        bf16x4 pk = { (__bf16)acc[0], (__bf16)acc[1], (__bf16)acc[2], (__bf16)acc[3] };
        int c = (nt - 16) * 16 + m16;
        *(bf16x4*)(v_g + ((size_t)i * HCC + c) * NN + mrow0 + mt * 16 + quad * 4) = pk;
      }
    }
  }
}

// Kernel B2: attention per (i,h), 512 threads / 8 waves.
// K,V staged in LDS once per block; S^T = K@Q^T with bias as C-operand;
// per-lane softmax; wave-private P strip; O^T = V^T@P^T packed stores.
__global__ __launch_bounds__(512, 1) void attn_kernel(
    const __bf16* __restrict__ q_g, const __bf16* __restrict__ k_g,
    const __bf16* __restrict__ v_g, const float* __restrict__ Zm,
    const float* __restrict__ bias, __bf16* __restrict__ wa)
{
  __shared__ __align__(16) __bf16 ks[NN * KSTR];        // K: [k_row][c]   30.0 KB
  __shared__ __align__(16) __bf16 vs[CH * PSTR];        // V^T: [c][k_row] 24.5 KB
  __shared__ __align__(16) __bf16 ps[8][16 * PSTR];     // per-wave P      98.0 KB
  __shared__ __align__(16) float maskb[NN];             //                  1.5 KB

  int i = blockIdx.x >> 2;
  int h = blockIdx.x & 3;
  int t = threadIdx.x;
  int wv = t >> 6, lane = t & 63;
  int m16 = lane & 15, quad = lane >> 4;

  // stage K: 384 rows x 4 groups of 8 ch
  for (int u = t; u < NN * 4; u += 512){
    int row = u >> 2, cg = u & 3;
    *(bf16x8*)(ks + row * KSTR + cg * 8) =
        *(const bf16x8*)(k_g + (size_t)(i * NN + row) * HCC + h * CH + cg * 8);
  }
  // stage V^T: 32 c-rows x 48 groups of 8 k
  for (int u = t; u < CH * 48; u += 512){
    int c = u / 48, kg = u - c * 48;
    *(bf16x8*)(vs + c * PSTR + kg * 8) =
        *(const bf16x8*)(v_g + ((size_t)i * HCC + h * CH + c) * NN + kg * 8);
  }
  if (t < NN) maskb[t] = (Zm[(size_t)i * NN + t] - 1.0f) * 1e9f;
  __syncthreads();

  __bf16* pw = ps[wv];
  const float* bh = bias + (size_t)h * NN * NN;

  for (int s = 0; s < 3; s++){
    int strip = wv * 3 + s;
    int qrow = strip * 16 + m16;
    bf16x8 qf = *(const bf16x8*)(q_g + (size_t)(i * NN + qrow) * HCC + h * CH + quad * 8);
    floatx4 sacc[24];
    #pragma unroll
    for (int kt = 0; kt < 24; kt++){
      int k0 = kt * 16 + quad * 4;
      floatx4 cin = *(const floatx4*)(bh + (size_t)qrow * NN + k0);
      floatx4 mk  = *(const floatx4*)(maskb + k0);
      cin += mk;
      bf16x8 kf = *(const bf16x8*)(ks + (kt * 16 + m16) * KSTR + quad * 8);
      sacc[kt] = __builtin_amdgcn_mfma_f32_16x16x32_bf16(kf, qf, cin, 0, 0, 0);
    }
    float mx = -1e30f;
    #pragma unroll
    for (int kt = 0; kt < 24; kt++)
      mx = fmaxf(mx, fmaxf(fmaxf(sacc[kt][0], sacc[kt][1]),
                           fmaxf(sacc[kt][2], sacc[kt][3])));
    mx = fmaxf(mx, __shfl_xor(mx, 16));
    mx = fmaxf(mx, __shfl_xor(mx, 32));
    float sm = 0.f;
    #pragma unroll
    for (int kt = 0; kt < 24; kt++){
      float p0 = __expf(sacc[kt][0] - mx);
      float p1 = __expf(sacc[kt][1] - mx);
      float p2 = __expf(sacc[kt][2] - mx);
      float p3 = __expf(sacc[kt][3] - mx);
      sm += (p0 + p1) + (p2 + p3);
      bf16x4 pk = { (__bf16)p0, (__bf16)p1, (__bf16)p2, (__bf16)p3 };
      *(bf16x4*)(pw + m16 * PSTR + kt * 16 + quad * 4) = pk;
    }
    sm += __shfl_xor(sm, 16);
    sm += __shfl_xor(sm, 32);
    float inv = 1.0f / sm;
    floatx4 oacc[2] = {{0.f,0.f,0.f,0.f},{0.f,0.f,0.f,0.f}};
    #pragma unroll
    for (int kc = 0; kc < 12; kc++){
      bf16x8 pa = *(const bf16x8*)(pw + m16 * PSTR + kc * 32 + quad * 8);
      #pragma unroll
      for (int ct = 0; ct < 2; ct++){
        bf16x8 vb = *(const bf16x8*)(vs + (ct * 16 + m16) * PSTR + kc * 32 + quad * 8);
        oacc[ct] = __builtin_amdgcn_mfma_f32_16x16x32_bf16(vb, pa, oacc[ct], 0, 0, 0);
      }
    }
    #pragma unroll
    for (int ct = 0; ct < 2; ct++){
      bf16x4 pk = { (__bf16)(oacc[ct][0] * inv), (__bf16)(oacc[ct][1] * inv),
                    (__bf16)(oacc[ct][2] * inv), (__bf16)(oacc[ct][3] * inv) };
      *(bf16x4*)(wa + (size_t)(i * NN + qrow) * HCC + h * CH + ct * 16 + quad * 4) = pk;
    }
  }
}

// Kernel C: 512 threads / 8 waves. gate = sigmoid(Zn@Wg+gb); out=(gate*wa)@Wo+Zr+ob
__global__ __launch_bounds__(512, 1) void out_kernel(
    const float* __restrict__ Zr, const __bf16* __restrict__ Zn,
    const __bf16* __restrict__ wa, const __bf16* __restrict__ WgT,
    const float* __restrict__ gb, const __bf16* __restrict__ WoT,
    const float* __restrict__ ob, float* __restrict__ out)
{
  __shared__ __align__(16) __bf16 wgs[128 * WSTRIDE];
  __shared__ __align__(16) __bf16 wos[128 * WSTRIDE];
  __shared__ __align__(16) __bf16 gsh[8][16 * WSTRIDE];
  __shared__ float gbs[HCC], obs[DP];

  int t = threadIdx.x;
  int wv = t >> 6, lane = t & 63;
  int m16 = lane & 15, quad = lane >> 4;

  for (int idx = t * 8; idx < 128 * 128; idx += 512 * 8){
    int r = idx >> 7, c = idx & 127;
    *(bf16x8*)(wgs + r * WSTRIDE + c) = *(const bf16x8*)(WgT + idx);
    *(bf16x8*)(wos + r * WSTRIDE + c) = *(const bf16x8*)(WoT + idx);
  }
  if (t < 128){ gbs[t] = gb[t]; obs[t] = ob[t]; }
  __syncthreads();

  int mbase = blockIdx.x * 256;
  __bf16* gstrip = gsh[wv];

  for (int sp = 0; sp < 2; sp++){
    int row0 = mbase + (sp * 8 + wv) * 16;
    bf16x8 afr[4];
    const __bf16* arow = Zn + (size_t)(row0 + m16) * DP + quad * 8;
    #pragma unroll
    for (int kc = 0; kc < 4; kc++) afr[kc] = *(const bf16x8*)(arow + kc * 32);
    #pragma unroll
    for (int nt = 0; nt < 8; nt++){
      floatx4 acc = {0.f, 0.f, 0.f, 0.f};
      #pragma unroll
      for (int kc = 0; kc < 4; kc++){
        bf16x8 bfr = *(const bf16x8*)(wgs + (nt * 16 + m16) * WSTRIDE + kc * 32 + quad * 8);
        acc = __builtin_amdgcn_mfma_f32_16x16x32_bf16(afr[kc], bfr, acc, 0, 0, 0);
      }
      int col = nt * 16 + m16;
      #pragma unroll
      for (int reg = 0; reg < 4; reg++){
        int row = row0 + quad * 4 + reg;
        float g = 1.0f / (1.0f + __expf(-(acc[reg] + gbs[col])));
        float w = __bfloat162float(wa[(size_t)row * HCC + col]);
        gstrip[(quad * 4 + reg) * WSTRIDE + col] = (__bf16)(g * w);
      }
    }
    bf16x8 gfr[4];
    #pragma unroll
    for (int kc = 0; kc < 4; kc++)
      gfr[kc] = *(const bf16x8*)(gstrip + m16 * WSTRIDE + kc * 32 + quad * 8);
    #pragma unroll
    for (int nt = 0; nt < 8; nt++){
      floatx4 acc = {0.f, 0.f, 0.f, 0.f};
      #pragma unroll
      for (int kc = 0; kc < 4; kc++){
        bf16x8 bfr = *(const bf16x8*)(wos + (nt * 16 + m16) * WSTRIDE + kc * 32 + quad * 8);
        acc = __builtin_amdgcn_mfma_f32_16x16x32_bf16(gfr[kc], bfr, acc, 0, 0, 0);
      }
      int col = nt * 16 + m16;
      #pragma unroll
      for (int reg = 0; reg < 4; reg++){
        int row = row0 + quad * 4 + reg;
        size_t off = (size_t)row * DP + col;
        out[off] = Zr[off] + acc[reg] + obs[col];
      }
    }
  }
}

extern "C" void kernel_launch(void* const* d_in, const int* in_sizes, int n_in,
                              void* d_out, int out_size, void* d_ws, size_t ws_size,
                              hipStream_t stream)
{
  const float* Zr   = (const float*)d_in[0];
  const float* Zm   = (const float*)d_in[1];
  const float* lnw  = (const float*)d_in[2];
  const float* lnb  = (const float*)d_in[3];
  const float* Wb   = (const float*)d_in[4];
  const float* Wqkv = (const float*)d_in[5];
  const float* Wg   = (const float*)d_in[6];
  const float* gb   = (const float*)d_in[7];
  const float* Wo   = (const float*)d_in[8];
  const float* ob   = (const float*)d_in[9];
  float* out = (float*)d_out;

  char* ws = (char*)d_ws;
  size_t off = 0;
  bf16*   Zn   = (bf16*)(ws + off);    off += (size_t)NN * NN * DP * 2;
  float*  bias = (float*)(ws + off);   off += (size_t)NHEAD * NN * NN * 4;
  bf16*   wa   = (bf16*)(ws + off);    off += (size_t)NN * NN * HCC * 2;
  __bf16* Wt   = (__bf16*)(ws + off);  off += (size_t)3 * HCC * DP * 2;
  __bf16* WgT  = (__bf16*)(ws + off);  off += (size_t)DP * HCC * 2;
  __bf16* WoT  = (__bf16*)(ws + off);  off += (size_t)HCC * DP * 2;
  __bf16* q_g  = (__bf16*)(ws + off);  off += (size_t)NN * NN * HCC * 2;
  __bf16* k_g  = (__bf16*)(ws + off);  off += (size_t)NN * NN * HCC * 2;
  __bf16* v_g  = (__bf16*)(ws + off);  off += (size_t)NN * HCC * NN * 2;

  prep_kernel<<<(3 * HCC * DP) / 256, 256, 0, stream>>>(Wqkv, Wg, Wo, Wt, WgT, WoT);
  ln_bias_kernel<<<NN * NN / 8, 256, 0, stream>>>(Zr, lnw, lnb, Wb, Zn, bias);
  qkv_gemm<<<NN * 2, 256, 0, stream>>>((const __bf16*)Zn, Wt, q_g, k_g, v_g);
  attn_kernel<<<NN * NHEAD, 512, 0, stream>>>(q_g, k_g, v_g, Zm, bias, (__bf16*)wa);
  out_kernel<<<NN * NN / 256, 512, 0, stream>>>(Zr, (const __bf16*)Zn, (const __bf16*)wa,
                                                WgT, gb, WoT, ob, out);
}